// Round 3
// baseline (376.463 us; speedup 1.0000x reference)
//
#include <hip/hip_runtime.h>
#include <cmath>

#define NLEVELS 16
#define HSIZE   (1 << 19)     // hashmap size, power of two
#define HMASK   (HSIZE - 1)

typedef float v2f __attribute__((ext_vector_type(2)));
typedef float v4f __attribute__((ext_vector_type(4)));

struct LevelParams {
    int res[NLEVELS];
    int r2mod[NLEVELS];       // (res*res) % HSIZE
};

__device__ __forceinline__ int hash_one(float x0, float x1, float x2, int res, int r2)
{
    const float fr = (float)res;
    int c0 = (int)floorf(x0 * fr); if (c0 >= res) c0 -= res;
    int c1 = (int)floorf(x1 * fr); if (c1 >= res) c1 -= res;
    int c2 = (int)floorf(x2 * fr); if (c2 >= res) c2 -= res;
    return (c0 + ((c1 * res) & HMASK) + ((c2 * r2) & HMASK)) & HMASK;
}

// ---------------- K1: XCD-affinity gather with cache routing -------------
// blockIdx%8 = g selects level pair {g, 15-g}; round-robin block->XCD keeps
// each pair's tables in one XCD's L2. Full-random tables are levels 5..15
// (11 tables, 4 MB hot each) -> pairs {5,10},{6,9},{7,8} would overflow the
// 4 MB L2. Fix: for g>=5, gather the coarse member (5/6/7) NON-TEMPORALLY so
// it never contends for L2; those reads are served by the L3 (all tables are
// L3-resident). Every XCD's cached footprint is then <= ~4.15 MB.
__global__ __launch_bounds__(256)
void hashgrid_gather(const float* __restrict__ x,
                     const float* __restrict__ emb,
                     v2f* __restrict__ ws,
                     LevelParams lp, int npts)
{
    __shared__ float sx[256 * 3];

    const int tid   = threadIdx.x;
    const int g     = blockIdx.x & 7;
    const int chunk = blockIdx.x >> 3;
    const int block_base = chunk * 256;

    const int nfl   = npts * 3;
    const int base3 = block_base * 3;
    #pragma unroll
    for (int k = 0; k < 3; ++k) {
        int idx = base3 + tid + k * 256;
        if (idx < nfl) sx[tid + k * 256] = __builtin_nontemporal_load(&x[idx]);
    }
    __syncthreads();

    const int p = block_base + tid;
    if (p >= npts) return;

    const float x0 = sx[tid * 3 + 0];
    const float x1 = sx[tid * 3 + 1];
    const float x2 = sx[tid * 3 + 2];

    const v2f* __restrict__ e2 = (const v2f*)emb;

    const int lA = g;          // coarse half (0..7); full-random for g>=5
    const int lB = 15 - g;     // fine half (8..15); always full-random, L2-affine

    const int hA = hash_one(x0, x1, x2, lp.res[lA], lp.r2mod[lA]);
    const int hB = hash_one(x0, x1, x2, lp.res[lB], lp.r2mod[lB]);

    v2f vA;
    if (g >= 5) {
        // L3-routed: don't let this 4 MB table evict lB's L2-resident table.
        vA = __builtin_nontemporal_load(&e2[(size_t)lA * HSIZE + hA]);
    } else {
        vA = e2[(size_t)lA * HSIZE + hA];   // small footprint, cache normally
    }
    const v2f vB = e2[(size_t)lB * HSIZE + hB];  // L2-affine 4 MB table

    __builtin_nontemporal_store(vA, &ws[(size_t)lA * npts + p]);
    __builtin_nontemporal_store(vB, &ws[(size_t)lB * npts + p]);
}

// ---------------- K2: level-major -> point-major via LDS transpose -------
// Phase A: thread t owns point p: 16 coalesced float2 plane reads
// (512 B/wave/level), parked in LDS (stride 17 float2 -> only free 2-way
// bank aliasing). Phase B: 8 rounds of per-instruction fully-contiguous
// 1 KB float4 NT stores.
__global__ __launch_bounds__(256)
void hashgrid_transpose(const v2f* __restrict__ ws,
                        v4f* __restrict__ out4, int npts)
{
    __shared__ v2f s2[256][17];

    const int tid = threadIdx.x;
    const int block_base = blockIdx.x * 256;
    const int p = block_base + tid;

    if (p < npts) {
        #pragma unroll
        for (int l = 0; l < NLEVELS; ++l)
            s2[tid][l] = ws[(size_t)l * npts + p];
    }
    __syncthreads();

    if (block_base + 256 <= npts) {
        #pragma unroll
        for (int i = 0; i < 8; ++i) {
            const int t  = i * 256 + tid;   // float4 index within block's 2048
            const int q  = t >> 3;          // local point
            const int j  = t & 7;           // float4 slot within point
            const v2f a = s2[q][2 * j];
            const v2f b = s2[q][2 * j + 1];
            v4f o; o.x = a.x; o.y = a.y; o.z = b.x; o.w = b.y;
            __builtin_nontemporal_store(o, &out4[(size_t)block_base * 8 + t]);
        }
    } else {
        // tail block (not hit for npts = 2^20, kept for safety)
        for (int i = 0; i < 8; ++i) {
            const int t = i * 256 + tid;
            const int q = t >> 3;
            if (block_base + q < npts) {
                const int j = t & 7;
                const v2f a = s2[q][2 * j];
                const v2f b = s2[q][2 * j + 1];
                v4f o; o.x = a.x; o.y = a.y; o.z = b.x; o.w = b.y;
                __builtin_nontemporal_store(o, &out4[(size_t)block_base * 8 + t]);
            }
        }
    }
}

// ---------------- fallback: proven round-1 single kernel -----------------
__global__ __launch_bounds__(256)
void hashgrid_fwd(const float* __restrict__ x,
                  const float* __restrict__ emb,
                  float* __restrict__ out,
                  LevelParams lp, int npts)
{
    __shared__ float sx[256 * 3];
    const int tid        = threadIdx.x;
    const int block_base = blockIdx.x * 256;
    const int nfl        = npts * 3;
    const int base3      = block_base * 3;
    #pragma unroll
    for (int k = 0; k < 3; ++k) {
        int idx = base3 + tid + k * 256;
        if (idx < nfl) sx[tid + k * 256] = x[idx];
    }
    __syncthreads();
    const int p = block_base + tid;
    if (p >= npts) return;
    const float x0 = sx[tid * 3 + 0], x1 = sx[tid * 3 + 1], x2 = sx[tid * 3 + 2];
    const float2* __restrict__ e2 = (const float2*)emb;
    float2 v[NLEVELS];
    #pragma unroll
    for (int l = 0; l < NLEVELS; ++l) {
        const int h = hash_one(x0, x1, x2, lp.res[l], lp.r2mod[l]);
        v[l] = e2[(size_t)l * HSIZE + h];
    }
    float4* __restrict__ o4 = (float4*)(out + (size_t)p * (NLEVELS * 2));
    #pragma unroll
    for (int i = 0; i < 8; ++i)
        o4[i] = make_float4(v[2 * i].x, v[2 * i].y, v[2 * i + 1].x, v[2 * i + 1].y);
}

extern "C" void kernel_launch(void* const* d_in, const int* in_sizes, int n_in,
                              void* d_out, int out_size, void* d_ws, size_t ws_size,
                              hipStream_t stream)
{
    const float* x   = (const float*)d_in[0];
    const float* emb = (const float*)d_in[1];
    float*       out = (float*)d_out;

    const int npts = in_sizes[0] / 3;

    // Host-double resolution computation, exact replica of the reference
    // (same libm as CPython's math.exp/log and float.**).
    LevelParams lp;
    const double s = std::exp((std::log(2048.0) - std::log(16.0)) / 15.0);
    for (int l = 0; l < NLEVELS; ++l) {
        const double r = 16.0 * std::pow(s, (double)l);
        const int res  = (int)r;
        lp.res[l]   = res;
        lp.r2mod[l] = (int)(((long long)res * res) % HSIZE);
    }

    const size_t ws_need = (size_t)NLEVELS * (size_t)npts * sizeof(v2f);
    if (ws_size >= ws_need) {
        const int chunks = (npts + 255) / 256;
        hipLaunchKernelGGL(hashgrid_gather, dim3(chunks * 8), dim3(256), 0, stream,
                           x, emb, (v2f*)d_ws, lp, npts);
        const int blocks2 = (npts + 255) / 256;
        hipLaunchKernelGGL(hashgrid_transpose, dim3(blocks2), dim3(256), 0, stream,
                           (const v2f*)d_ws, (v4f*)out, npts);
    } else {
        const int blocks = (npts + 255) / 256;
        hipLaunchKernelGGL(hashgrid_fwd, dim3(blocks), dim3(256), 0, stream,
                           x, emb, out, lp, npts);
    }
}